// Round 14
// baseline (157.818 us; speedup 1.0000x reference)
//
#include <hip/hip_runtime.h>
#include <hip/hip_bf16.h>
#include <hip/hip_fp16.h>

// out[bn,e] = relu(relu(hp[bn]+ep[e]+b1) @ W2 + b2) @ W3 + b3
// R18 = 32x32x16 MFMA (17% fewer matrix cycles, 0 bank conflicts w/ ^(r&31)
// swizzle — both measured in R16) executed in R15-SIZED scheduling regions:
// each iteration fuses TWO K=16 slots -> 4 ds_reads + 16 MFMA + 8 B loads
// (~260 matrix-cy), so the per-region A-read latency (~120cy) is hidden as
// in R15. R16/R17's regression mechanism (65cy steps exposing that latency
// every step) is thereby removed. Topology/staging/epilogue = R15/R16 best:
// 2048 blk x 256 thr, 2 blk/CU, wave = 64r x 128c, setprio, peeled tail,
// 16-position stagger, f16 datapath. Regs: 64 B-frag + 16 A + 128 acc = 256.

typedef __attribute__((ext_vector_type(8))) _Float16 f16x8;   // 8 f16 (4 VGPR)
typedef __attribute__((ext_vector_type(16))) float f32x16;    // 32x32 MFMA acc

static __device__ __forceinline__ ushort2 pk_f16(float a, float b) {
  union { __half2 h; ushort2 u; } c;
  c.h = __float22half2_rn(make_float2(a, b));
  return c.u;
}

// ---------------- fused prep (352 blocks x 256 thr) ----------------
// blocks 0..255  : hpb rows (2/blk)  hpb[r][k] = f16(sum_h h[r][h]*W1[h][k] + b1[k])
// blocks 256..287: epb rows (8/blk)  epb[e][k] = f16(sum_d e[e][d]*W1[256+d][k])
// blocks 288..351: w2f pack for 32x32x16 B-frags:
//   record(jg 0..15, ks 0..31): lane l holds W2[k = ks*16+(l>>5)*8+u][col = jg*32+(l&31)]
__global__ __launch_bounds__(256) void k_prep(
    const float* __restrict__ h_all, const float* __restrict__ e_feat,
    const float* __restrict__ W1, const float* __restrict__ b1,
    const float* __restrict__ W2,
    unsigned short* __restrict__ hpb, unsigned short* __restrict__ epb,
    unsigned short* __restrict__ w2f) {
  __shared__ float sm[64 * 68];   // 17408 B, reused per role
  const int t = threadIdx.x;
  const int b = blockIdx.x;

  if (b < 256) {                      // ---- hp part: 2 rows, f16 out
    const int r0 = b * 2;
    float (*hs)[256] = (float(*)[256])sm;
    hs[0][t] = h_all[(size_t)r0 * 256 + t];
    hs[1][t] = h_all[(size_t)(r0 + 1) * 256 + t];
    __syncthreads();
    float2 a0 = make_float2(0.f, 0.f), a1 = make_float2(0.f, 0.f);
    #pragma unroll 2
    for (int k = 0; k < 256; k += 4) {
      float2 w0 = *(const float2*)(W1 + (size_t)k * 512 + 2 * t);
      float2 w1 = *(const float2*)(W1 + (size_t)(k + 1) * 512 + 2 * t);
      float2 w2v = *(const float2*)(W1 + (size_t)(k + 2) * 512 + 2 * t);
      float2 w3v = *(const float2*)(W1 + (size_t)(k + 3) * 512 + 2 * t);
      float h00 = hs[0][k], h01 = hs[0][k + 1], h02 = hs[0][k + 2], h03 = hs[0][k + 3];
      float h10 = hs[1][k], h11 = hs[1][k + 1], h12 = hs[1][k + 2], h13 = hs[1][k + 3];
      a0.x = fmaf(h00, w0.x, a0.x); a0.y = fmaf(h00, w0.y, a0.y);
      a1.x = fmaf(h10, w0.x, a1.x); a1.y = fmaf(h10, w0.y, a1.y);
      a0.x = fmaf(h01, w1.x, a0.x); a0.y = fmaf(h01, w1.y, a0.y);
      a1.x = fmaf(h11, w1.x, a1.x); a1.y = fmaf(h11, w1.y, a1.y);
      a0.x = fmaf(h02, w2v.x, a0.x); a0.y = fmaf(h02, w2v.y, a0.y);
      a1.x = fmaf(h12, w2v.x, a1.x); a1.y = fmaf(h12, w2v.y, a1.y);
      a0.x = fmaf(h03, w3v.x, a0.x); a0.y = fmaf(h03, w3v.y, a0.y);
      a1.x = fmaf(h13, w3v.x, a1.x); a1.y = fmaf(h13, w3v.y, a1.y);
    }
    float2 bv = *(const float2*)(b1 + 2 * t);
    *(ushort2*)(hpb + (size_t)r0 * 512 + 2 * t) = pk_f16(a0.x + bv.x, a0.y + bv.y);
    *(ushort2*)(hpb + (size_t)(r0 + 1) * 512 + 2 * t) = pk_f16(a1.x + bv.x, a1.y + bv.y);
  } else if (b < 288) {               // ---- ep part: 8 rows, f16 out
    const int r0 = (b - 256) * 8;
    sm[t] = e_feat[(size_t)r0 * 64 + t];
    sm[256 + t] = e_feat[(size_t)r0 * 64 + 256 + t];
    __syncthreads();
    float2 acc[8];
    #pragma unroll
    for (int i = 0; i < 8; ++i) acc[i] = make_float2(0.f, 0.f);
    for (int k = 0; k < 64; ++k) {
      float2 wv = *(const float2*)(W1 + (size_t)(256 + k) * 512 + 2 * t);
      #pragma unroll
      for (int i = 0; i < 8; ++i) {
        acc[i].x = fmaf(sm[i * 64 + k], wv.x, acc[i].x);
        acc[i].y = fmaf(sm[i * 64 + k], wv.y, acc[i].y);
      }
    }
    #pragma unroll
    for (int i = 0; i < 8; ++i)
      *(ushort2*)(epb + (size_t)(r0 + i) * 512 + 2 * t) = pk_f16(acc[i].x, acc[i].y);
  } else {                            // ---- w2f pack (32x32x16 records)
    const int bbk = b - 288;          // 0..63
    const int k0 = (bbk >> 3) * 64;
    const int c0 = (bbk & 7) * 64;
    #pragma unroll
    for (int rr = 0; rr < 4; ++rr) {
      const int row = rr * 16 + (t >> 4);
      float4 v = *(const float4*)(W2 + (size_t)(k0 + row) * 512 + c0 + (t & 15) * 4);
      *(float4*)(&sm[row * 68 + (t & 15) * 4]) = v;
    }
    __syncthreads();
    #pragma unroll
    for (int s2 = 0; s2 < 2; ++s2) {
      const int s = t * 2 + s2;       // 0..511 (8 records x 64 lanes)
      const int rec = s >> 6, l = s & 63;
      const int jg = (c0 >> 5) + (rec & 1);        // col-tile of 32
      const int ks = (k0 >> 4) + (rec >> 1);       // k-step of 16
      const int cl = (rec & 1) * 32 + (l & 31);
      const int kl = (rec >> 1) * 16 + (l >> 5) * 8;
      union { ushort2 o[4]; uint4 v; } u;
      #pragma unroll
      for (int uu = 0; uu < 4; ++uu)
        u.o[uu] = pk_f16(sm[(kl + 2 * uu) * 68 + cl], sm[(kl + 2 * uu + 1) * 68 + cl]);
      *(uint4*)(w2f + ((size_t)(jg * 32 + ks) * 64 + l) * 8) = u.v;
    }
  }
}

// ---------------- main fused kernel ----------------
// 2048 blocks x 256 thr. Block = 64 rows (one bn, e-quarter) x all 512 cols.
// Wave w: col-tiles jg = w*4..+4 (128 cols), rows 0..63 (2 row-tiles of 32).
// 16 iterations, each fusing TWO K=16 slots: 4 ds_reads + 16 MFMA + 8 B loads.
// LDS swizzle: chunk' = chunk ^ (row&31) (measured 0 conflicts in R16).
__global__ __launch_bounds__(256, 2) void k_main(
    const unsigned short* __restrict__ hpb, const unsigned short* __restrict__ epb,
    const unsigned short* __restrict__ w2f, const float* __restrict__ b2,
    const float* __restrict__ W3, const float* __restrict__ b3,
    float* __restrict__ out) {
  __shared__ unsigned short x1s[64 * 512];   // 64 KiB

  const int t = threadIdx.x;
  const int lane = t & 63;
  const int w = t >> 6;          // 0..3 -> col group (128 cols)
  const int l31 = lane & 31, l5 = lane >> 5;
  const int bn = blockIdx.x >> 2;
  const int e0 = (blockIdx.x & 3) << 6;
  const int off = (blockIdx.x * 11) & 15;   // stagger in slot-PAIR units
  const unsigned short* hprow = hpb + (size_t)bn * 512;

  // B-frag ping-pong over slot pairs; wave w owns jg = w*4..+4
  const unsigned short* wrec = w2f + (size_t)w * 65536 + (size_t)lane * 8;
  f16x8 bb0[2][4], bb1[2][4];     // B for even/odd slot of each buffered pair
  #pragma unroll
  for (int d = 0; d < 2; ++d) {
    const int sp = 2 * ((d + off) & 15);
    #pragma unroll
    for (int j = 0; j < 4; ++j) {
      bb0[d][j] = *(const f16x8*)(wrec + j * 16384 + (size_t)sp * 512);
      bb1[d][j] = *(const f16x8*)(wrec + j * 16384 + (size_t)(sp + 1) * 512);
    }
  }

  // ---- stage x1 once: relu(hp + ep) -> f16 (packed), chunk' = chunk ^ (r&31)
  {
    const int kk = t & 63;          // 16B-chunk index (8 f16)
    const int rbase = t >> 6;       // 0..3
    const f16x8 fz = {0, 0, 0, 0, 0, 0, 0, 0};
    const f16x8 hv = *(const f16x8*)(hprow + kk * 8);
    #pragma unroll 2
    for (int rr = 0; rr < 16; ++rr) {
      const int r = rr * 4 + rbase;
      f16x8 ev = *(const f16x8*)(epb + (size_t)(e0 + r) * 512 + kk * 8);
      f16x8 x = hv + ev;
      x = __builtin_elementwise_max(x, fz);
      *(f16x8*)(&x1s[r * 512 + ((kk ^ (r & 31)) * 8)]) = x;
    }
  }
  __syncthreads();

  f32x16 acc[2][4] = {};
  // steady iterations 0..13: 4 A-reads, 16 MFMA (prio-boosted), 8 B prefetch
  #pragma unroll 2
  for (int it = 0; it < 14; ++it) {
    const int cur = it & 1;
    const int sp = 2 * ((it + off) & 15);        // this iter's slot pair
    const int spb = 2 * ((it + 2 + off) & 15);   // prefetch pair (valid)
    f16x8 a[2], a2[2];
    #pragma unroll
    for (int i = 0; i < 2; ++i) {
      const int r = i * 32 + l31;
      a[i]  = *(const f16x8*)(&x1s[r * 512 + ((((sp * 2) + l5) ^ l31) * 8)]);
      a2[i] = *(const f16x8*)(&x1s[r * 512 + ((((sp * 2 + 2) + l5) ^ l31) * 8)]);
    }
    __builtin_amdgcn_s_setprio(1);
    #pragma unroll
    for (int i = 0; i < 2; ++i)
      #pragma unroll
      for (int j = 0; j < 4; ++j)
        acc[i][j] = __builtin_amdgcn_mfma_f32_32x32x16_f16(a[i], bb0[cur][j], acc[i][j], 0, 0, 0);
    #pragma unroll
    for (int i = 0; i < 2; ++i)
      #pragma unroll
      for (int j = 0; j < 4; ++j)
        acc[i][j] = __builtin_amdgcn_mfma_f32_32x32x16_f16(a2[i], bb1[cur][j], acc[i][j], 0, 0, 0);
    __builtin_amdgcn_s_setprio(0);
    #pragma unroll
    for (int j = 0; j < 4; ++j) {
      bb0[cur][j] = *(const f16x8*)(wrec + j * 16384 + (size_t)spb * 512);
      bb1[cur][j] = *(const f16x8*)(wrec + j * 16384 + (size_t)(spb + 1) * 512);
    }
  }
  // tail iterations 14,15: consume last prefetched pairs, no reloads
  #pragma unroll
  for (int it = 14; it < 16; ++it) {
    const int cur = it & 1;
    const int sp = 2 * ((it + off) & 15);
    f16x8 a[2], a2[2];
    #pragma unroll
    for (int i = 0; i < 2; ++i) {
      const int r = i * 32 + l31;
      a[i]  = *(const f16x8*)(&x1s[r * 512 + ((((sp * 2) + l5) ^ l31) * 8)]);
      a2[i] = *(const f16x8*)(&x1s[r * 512 + ((((sp * 2 + 2) + l5) ^ l31) * 8)]);
    }
    __builtin_amdgcn_s_setprio(1);
    #pragma unroll
    for (int i = 0; i < 2; ++i)
      #pragma unroll
      for (int j = 0; j < 4; ++j)
        acc[i][j] = __builtin_amdgcn_mfma_f32_32x32x16_f16(a[i], bb0[cur][j], acc[i][j], 0, 0, 0);
    #pragma unroll
    for (int i = 0; i < 2; ++i)
      #pragma unroll
      for (int j = 0; j < 4; ++j)
        acc[i][j] = __builtin_amdgcn_mfma_f32_32x32x16_f16(a2[i], bb1[cur][j], acc[i][j], 0, 0, 0);
    __builtin_amdgcn_s_setprio(0);
  }

  // ---- fused epilogue: osum[row] = sum_n relu(acc + b2[n]) * W3[n]
  // C layout (32x32): col = lane&31, row = (reg&3) + 8*(reg>>2) + 4*(lane>>5)
  float part[2][16];
  #pragma unroll
  for (int i = 0; i < 2; ++i)
    #pragma unroll
    for (int r = 0; r < 16; ++r) part[i][r] = 0.f;
  #pragma unroll
  for (int j = 0; j < 4; ++j) {
    const int n = w * 128 + j * 32 + l31;
    const float b2v = b2[n], w3v = W3[n];
    #pragma unroll
    for (int i = 0; i < 2; ++i)
      #pragma unroll
      for (int r = 0; r < 16; ++r)
        part[i][r] = fmaf(fmaxf(acc[i][j][r] + b2v, 0.f), w3v, part[i][r]);
  }
  #pragma unroll
  for (int i = 0; i < 2; ++i)
    #pragma unroll
    for (int r = 0; r < 16; ++r) {   // reduce over the 32 col-lanes (l31)
      float v = part[i][r];
      v += __shfl_xor(v, 1);
      v += __shfl_xor(v, 2);
      v += __shfl_xor(v, 4);
      v += __shfl_xor(v, 8);
      v += __shfl_xor(v, 16);
      part[i][r] = v;
    }
  __syncthreads();                   // all x1s reads done before aliasing
  float* osum = (float*)x1s;         // [4 col-groups][64 rows]
  if (l31 == 0) {
    #pragma unroll
    for (int i = 0; i < 2; ++i)
      #pragma unroll
      for (int r = 0; r < 16; ++r)
        osum[w * 64 + i * 32 + (r & 3) + 8 * (r >> 2) + 4 * l5] = part[i][r];
  }
  __syncthreads();
  if (t < 64) {
    float s = b3[0] + osum[t] + osum[64 + t] + osum[128 + t] + osum[192 + t];
    out[(size_t)bn * 256 + e0 + t] = s;
  }
}

extern "C" void kernel_launch(void* const* d_in, const int* in_sizes, int n_in,
                              void* d_out, int out_size, void* d_ws, size_t ws_size,
                              hipStream_t stream) {
  const float* h_all  = (const float*)d_in[0];   // (8,64,256)
  const float* e_feat = (const float*)d_in[1];   // (256,64)
  const float* W1     = (const float*)d_in[2];   // (320,512)
  const float* b1     = (const float*)d_in[3];   // (512,)
  const float* W2     = (const float*)d_in[4];   // (512,512)
  const float* b2     = (const float*)d_in[5];   // (512,)
  const float* W3     = (const float*)d_in[6];   // (512,1)
  const float* b3     = (const float*)d_in[7];   // (1,)
  float* out = (float*)d_out;                    // 131072 f32

  // workspace: hpb 512KB f16 | epb 256KB f16 | w2f 512KB f16
  unsigned short* hpb = (unsigned short*)d_ws;
  unsigned short* epb = hpb + 512 * 512;
  unsigned short* w2f = epb + 256 * 512;

  hipLaunchKernelGGL(k_prep, dim3(352), dim3(256), 0, stream,
                     h_all, e_feat, W1, b1, W2, hpb, epb, w2f);
  hipLaunchKernelGGL(k_main, dim3(2048), dim3(256), 0, stream,
                     hpb, epb, w2f, b2, W3, b3, out);
}

// Round 15
// 140.090 us; speedup vs baseline: 1.1265x; 1.1265x over previous
//
#include <hip/hip_runtime.h>
#include <hip/hip_bf16.h>
#include <hip/hip_fp16.h>

// out[bn,e] = relu(relu(hp[bn]+ep[e]+b1) @ W2 + b2) @ W3 + b3
// R19 = R15 (best: 140.7 total / 68.5 k_main — f16 datapath, 64-row blocks,
// XOR LDS, depth-2 B ping-pong, 16-slot stagger, setprio, peeled tail)
// + two schedule-only tweaks: staging unroll 2->4 (more ep loads in flight
// during the latency-bound staging phase), steady K-loop unroll 2->4
// (wider interleave window for B-reloads vs next A-reads).
// 32x32 MFMA line closed: R16/R17/R18 all 88-92us despite 0 conflicts.

typedef __attribute__((ext_vector_type(8))) _Float16 f16x8;  // 8 f16 (4 VGPR)
typedef __attribute__((ext_vector_type(4))) float f32x4;     // MFMA acc

static __device__ __forceinline__ ushort2 pk_f16(float a, float b) {
  union { __half2 h; ushort2 u; } c;
  c.h = __float22half2_rn(make_float2(a, b));
  return c.u;
}

// ---------------- fused prep (352 blocks x 256 thr) ----------------
// blocks 0..255  : hpb rows (2/blk)  hpb[r][k] = f16(sum_h h[r][h]*W1[h][k] + b1[k])
// blocks 256..287: epb rows (8/blk)  epb[e][k] = f16(sum_d e[e][d]*W1[256+d][k])
// blocks 288..351: w2f pack (64x64 W2 tile -> f16 B-frag records, 16x16x32)
//   record(jg,ks): lane l holds W2[k = ks*32+(l>>4)*8 + u][col = jg*16+(l&15)], u=0..7
__global__ __launch_bounds__(256) void k_prep(
    const float* __restrict__ h_all, const float* __restrict__ e_feat,
    const float* __restrict__ W1, const float* __restrict__ b1,
    const float* __restrict__ W2,
    unsigned short* __restrict__ hpb, unsigned short* __restrict__ epb,
    unsigned short* __restrict__ w2f) {
  __shared__ float sm[64 * 68];   // 17408 B, reused per role
  const int t = threadIdx.x;
  const int b = blockIdx.x;

  if (b < 256) {                      // ---- hp part: 2 rows, f16 out
    const int r0 = b * 2;
    float (*hs)[256] = (float(*)[256])sm;
    hs[0][t] = h_all[(size_t)r0 * 256 + t];
    hs[1][t] = h_all[(size_t)(r0 + 1) * 256 + t];
    __syncthreads();
    float2 a0 = make_float2(0.f, 0.f), a1 = make_float2(0.f, 0.f);
    #pragma unroll 2
    for (int k = 0; k < 256; k += 4) {
      float2 w0 = *(const float2*)(W1 + (size_t)k * 512 + 2 * t);
      float2 w1 = *(const float2*)(W1 + (size_t)(k + 1) * 512 + 2 * t);
      float2 w2v = *(const float2*)(W1 + (size_t)(k + 2) * 512 + 2 * t);
      float2 w3v = *(const float2*)(W1 + (size_t)(k + 3) * 512 + 2 * t);
      float h00 = hs[0][k], h01 = hs[0][k + 1], h02 = hs[0][k + 2], h03 = hs[0][k + 3];
      float h10 = hs[1][k], h11 = hs[1][k + 1], h12 = hs[1][k + 2], h13 = hs[1][k + 3];
      a0.x = fmaf(h00, w0.x, a0.x); a0.y = fmaf(h00, w0.y, a0.y);
      a1.x = fmaf(h10, w0.x, a1.x); a1.y = fmaf(h10, w0.y, a1.y);
      a0.x = fmaf(h01, w1.x, a0.x); a0.y = fmaf(h01, w1.y, a0.y);
      a1.x = fmaf(h11, w1.x, a1.x); a1.y = fmaf(h11, w1.y, a1.y);
      a0.x = fmaf(h02, w2v.x, a0.x); a0.y = fmaf(h02, w2v.y, a0.y);
      a1.x = fmaf(h12, w2v.x, a1.x); a1.y = fmaf(h12, w2v.y, a1.y);
      a0.x = fmaf(h03, w3v.x, a0.x); a0.y = fmaf(h03, w3v.y, a0.y);
      a1.x = fmaf(h13, w3v.x, a1.x); a1.y = fmaf(h13, w3v.y, a1.y);
    }
    float2 bv = *(const float2*)(b1 + 2 * t);
    *(ushort2*)(hpb + (size_t)r0 * 512 + 2 * t) = pk_f16(a0.x + bv.x, a0.y + bv.y);
    *(ushort2*)(hpb + (size_t)(r0 + 1) * 512 + 2 * t) = pk_f16(a1.x + bv.x, a1.y + bv.y);
  } else if (b < 288) {               // ---- ep part: 8 rows, f16 out
    const int r0 = (b - 256) * 8;
    sm[t] = e_feat[(size_t)r0 * 64 + t];
    sm[256 + t] = e_feat[(size_t)r0 * 64 + 256 + t];
    __syncthreads();
    float2 acc[8];
    #pragma unroll
    for (int i = 0; i < 8; ++i) acc[i] = make_float2(0.f, 0.f);
    for (int k = 0; k < 64; ++k) {
      float2 wv = *(const float2*)(W1 + (size_t)(256 + k) * 512 + 2 * t);
      #pragma unroll
      for (int i = 0; i < 8; ++i) {
        acc[i].x = fmaf(sm[i * 64 + k], wv.x, acc[i].x);
        acc[i].y = fmaf(sm[i * 64 + k], wv.y, acc[i].y);
      }
    }
    #pragma unroll
    for (int i = 0; i < 8; ++i)
      *(ushort2*)(epb + (size_t)(r0 + i) * 512 + 2 * t) = pk_f16(acc[i].x, acc[i].y);
  } else {                            // ---- w2f pack
    const int bb = b - 288;           // 0..63
    const int k0 = (bb >> 3) * 64;
    const int c0 = (bb & 7) * 64;
    #pragma unroll
    for (int rr = 0; rr < 4; ++rr) {
      const int row = rr * 16 + (t >> 4);
      float4 v = *(const float4*)(W2 + (size_t)(k0 + row) * 512 + c0 + (t & 15) * 4);
      *(float4*)(&sm[row * 68 + (t & 15) * 4]) = v;
    }
    __syncthreads();
    #pragma unroll
    for (int s2 = 0; s2 < 2; ++s2) {
      const int s = t * 2 + s2;       // 0..511 (8 records x 64 lanes)
      const int rec = s >> 6, l = s & 63;
      const int jg = (c0 >> 4) + (rec & 3);
      const int ksg = (k0 >> 5) + (rec >> 2);
      const int cl = (rec & 3) * 16 + (l & 15);
      const int kl = (rec >> 2) * 32 + (l >> 4) * 8;
      union { ushort2 o[4]; uint4 v; } u;
      #pragma unroll
      for (int uu = 0; uu < 4; ++uu)
        u.o[uu] = pk_f16(sm[(kl + 2 * uu) * 68 + cl], sm[(kl + 2 * uu + 1) * 68 + cl]);
      *(uint4*)(w2f + ((size_t)(jg * 16 + ksg) * 64 + l) * 8) = u.v;
    }
  }
}

// ---------------- main fused kernel ----------------
// 2048 blocks x 256 thr. Block = 64 rows (one bn, e-quarter) x all 512 cols.
// Wave w: cols w*128..+128 (j=0..7), rows 0..63 (i=0..3).
// Depth-2 B prefetch ping-pong; per-block K stagger. All-f16 datapath.
// setprio around MFMA nest; last 2 K-steps peeled (no dummy B reloads).
__global__ __launch_bounds__(256, 2) void k_main(
    const unsigned short* __restrict__ hpb, const unsigned short* __restrict__ epb,
    const unsigned short* __restrict__ w2f, const float* __restrict__ b2,
    const float* __restrict__ W3, const float* __restrict__ b3,
    float* __restrict__ out) {
  __shared__ unsigned short x1s[64 * 512];   // 64 KiB, XOR-swizzled 16B chunks

  const int t = threadIdx.x;
  const int lane = t & 63;
  const int w = t >> 6;          // 0..3 -> col group (128 cols)
  const int l15 = lane & 15, l4 = lane >> 4;
  const int bn = blockIdx.x >> 2;
  const int e0 = (blockIdx.x & 3) << 6;
  const int off = (blockIdx.x * 11) & 15;   // K stagger
  const unsigned short* hprow = hpb + (size_t)bn * 512;

  // b-frag ping-pong; preload ks-slot 0 and 1 (in flight across staging)
  const unsigned short* wrec = w2f + (size_t)w * 65536 + (size_t)lane * 8;
  f16x8 bb[2][8];
  #pragma unroll
  for (int j = 0; j < 8; ++j) {
    bb[0][j] = *(const f16x8*)(wrec + j * 8192 + (size_t)off * 512);
    bb[1][j] = *(const f16x8*)(wrec + j * 8192 + (size_t)((off + 1) & 15) * 512);
  }

  // ---- stage x1 once: relu(hp + ep) -> f16 (packed pk_add/pk_max),
  // chunk' = chunk ^ (row&7)
  {
    const int kk = t & 63;          // 16B-chunk index (8 f16)
    const int rbase = t >> 6;       // 0..3
    const f16x8 fz = {0, 0, 0, 0, 0, 0, 0, 0};
    const f16x8 hv = *(const f16x8*)(hprow + kk * 8);
    #pragma unroll 4
    for (int rr = 0; rr < 16; ++rr) {
      const int r = rr * 4 + rbase;
      f16x8 ev = *(const f16x8*)(epb + (size_t)(e0 + r) * 512 + kk * 8);
      f16x8 x = hv + ev;
      x = __builtin_elementwise_max(x, fz);
      *(f16x8*)(&x1s[r * 512 + (kk ^ (r & 7)) * 8]) = x;
    }
  }
  __syncthreads();

  f32x4 acc[4][8] = {};
  // steady steps 0..13: A-reads, MFMA nest (prio-boosted), B prefetch for ks+2
  #pragma unroll 4
  for (int ks = 0; ks < 14; ++ks) {
    const int cur = ks & 1;
    const int kr = (ks + off) & 15;        // this iter's k-slot
    const int krb = (ks + 2 + off) & 15;   // prefetch slot (always valid here)
    f16x8 a[4];
    #pragma unroll
    for (int i = 0; i < 4; ++i) {
      const int r = i * 16 + l15;          // r&7 == l15&7
      a[i] = *(const f16x8*)(&x1s[r * 512 + (((kr * 4 + l4) ^ (l15 & 7)) * 8)]);
    }
    __builtin_amdgcn_s_setprio(1);
    #pragma unroll
    for (int i = 0; i < 4; ++i)
      #pragma unroll
      for (int j = 0; j < 8; ++j)
        acc[i][j] = __builtin_amdgcn_mfma_f32_16x16x32_f16(a[i], bb[cur][j], acc[i][j], 0, 0, 0);
    __builtin_amdgcn_s_setprio(0);
    #pragma unroll
    for (int j = 0; j < 8; ++j)
      bb[cur][j] = *(const f16x8*)(wrec + j * 8192 + (size_t)krb * 512);
  }
  // tail steps 14,15: consume the last prefetched slots, no B reloads
  #pragma unroll
  for (int ks = 14; ks < 16; ++ks) {
    const int cur = ks & 1;
    const int kr = (ks + off) & 15;
    f16x8 a[4];
    #pragma unroll
    for (int i = 0; i < 4; ++i) {
      const int r = i * 16 + l15;
      a[i] = *(const f16x8*)(&x1s[r * 512 + (((kr * 4 + l4) ^ (l15 & 7)) * 8)]);
    }
    __builtin_amdgcn_s_setprio(1);
    #pragma unroll
    for (int i = 0; i < 4; ++i)
      #pragma unroll
      for (int j = 0; j < 8; ++j)
        acc[i][j] = __builtin_amdgcn_mfma_f32_16x16x32_f16(a[i], bb[cur][j], acc[i][j], 0, 0, 0);
    __builtin_amdgcn_s_setprio(0);
  }

  // ---- fused epilogue: osum[row] = sum_n relu(acc + b2[n]) * W3[n]
  float part[16];
  #pragma unroll
  for (int u = 0; u < 16; ++u) part[u] = 0.f;
  #pragma unroll
  for (int j = 0; j < 8; ++j) {
    const int n = w * 128 + j * 16 + l15;
    const float b2v = b2[n], w3v = W3[n];
    #pragma unroll
    for (int i = 0; i < 4; ++i)
      #pragma unroll
      for (int r = 0; r < 4; ++r)
        part[i * 4 + r] = fmaf(fmaxf(acc[i][j][r] + b2v, 0.f), w3v, part[i * 4 + r]);
  }
  #pragma unroll
  for (int u = 0; u < 16; ++u) {     // reduce over the 16 col-lanes (l15)
    float v = part[u];
    v += __shfl_xor(v, 1);
    v += __shfl_xor(v, 2);
    v += __shfl_xor(v, 4);
    v += __shfl_xor(v, 8);
    part[u] = v;
  }
  __syncthreads();                   // all x1s reads done before aliasing
  float* osum = (float*)x1s;         // [4 col-groups][64 rows]
  if (l15 == 0) {
    #pragma unroll
    for (int i = 0; i < 4; ++i)
      #pragma unroll
      for (int r = 0; r < 4; ++r)
        osum[w * 64 + i * 16 + l4 * 4 + r] = part[i * 4 + r];
  }
  __syncthreads();
  if (t < 64) {
    float s = b3[0] + osum[t] + osum[64 + t] + osum[128 + t] + osum[192 + t];
    out[(size_t)bn * 256 + e0 + t] = s;
  }
}

extern "C" void kernel_launch(void* const* d_in, const int* in_sizes, int n_in,
                              void* d_out, int out_size, void* d_ws, size_t ws_size,
                              hipStream_t stream) {
  const float* h_all  = (const float*)d_in[0];   // (8,64,256)
  const float* e_feat = (const float*)d_in[1];   // (256,64)
  const float* W1     = (const float*)d_in[2];   // (320,512)
  const float* b1     = (const float*)d_in[3];   // (512,)
  const float* W2     = (const float*)d_in[4];   // (512,512)
  const float* b2     = (const float*)d_in[5];   // (512,)
  const float* W3     = (const float*)d_in[6];   // (512,1)
  const float* b3     = (const float*)d_in[7];   // (1,)
  float* out = (float*)d_out;                    // 131072 f32

  // workspace: hpb 512KB f16 | epb 256KB f16 | w2f 512KB f16
  unsigned short* hpb = (unsigned short*)d_ws;
  unsigned short* epb = hpb + 512 * 512;
  unsigned short* w2f = epb + 256 * 512;

  hipLaunchKernelGGL(k_prep, dim3(352), dim3(256), 0, stream,
                     h_all, e_feat, W1, b1, W2, hpb, epb, w2f);
  hipLaunchKernelGGL(k_main, dim3(2048), dim3(256), 0, stream,
                     hpb, epb, w2f, b2, W3, b3, out);
}